// Round 9
// baseline (276.278 us; speedup 1.0000x reference)
//
#include <hip/hip_runtime.h>
#include <math.h>

// ---------------------------------------------------------------------------
// SheafGNN forward. R23 = R22 (273.5us, k_conv 54.4us, VGPR 72) +
//  - k_conv: epilogue-only state (xi1/xi2/hv1/hv2 = 10 VGPRs) loaded AFTER
//    the batch loop, not at node entry. R22 held them live across the whole
//    loop and crossed the 64-VGPR cliff (occ 25% vs 33% at <=64). Ledger:
//    VGPR 64 -> 33% occ (R15/R19); VGPR 68-72 -> 22-25% occ (R16/R17/R22).
//    Latency-bound kernel: resident waves ~ 1/duration.
// Pinned: 1-wave WGs; hdr parallel entry; xs dbuf staging + counted vmcnt;
// per-wave lgkm fences; never force occupancy via launch_bounds (R18).
// ---------------------------------------------------------------------------

using short8 = __attribute__((ext_vector_type(8))) short;
using f32x4 = __attribute__((ext_vector_type(4))) float;
typedef unsigned short u16;

__device__ __forceinline__ u16 f2bf(float f) {  // RNE fp32->bf16
  unsigned u = __float_as_uint(f);
  unsigned r = (u + 0x7FFFu + ((u >> 16) & 1u)) >> 16;
  return (u16)r;
}
__device__ __forceinline__ float bf2f(u16 v) {
  return __uint_as_float(((unsigned)v) << 16);
}

// per-wave LDS fence (1-wave block): orders ds_write -> ds_read without
// draining vmcnt (keeps global_load_lds prefetches in flight).
__device__ __forceinline__ void wave_sync() {
  __builtin_amdgcn_sched_barrier(0);
  asm volatile("s_waitcnt lgkmcnt(0)" ::: "memory");
  __builtin_amdgcn_sched_barrier(0);
}

// async 16B/lane global->LDS: HW dest = lds_base + lane*16 (wave-uniform
// base); global src is per-lane. Tracked by vmcnt.
__device__ __forceinline__ void glds16(const void* g, void* l) {
  __builtin_amdgcn_global_load_lds(
      (const __attribute__((address_space(1))) unsigned int*)g,
      (__attribute__((address_space(3))) unsigned int*)l, 16, 0, 0);
}

// ---- fused one-time prep: x->bf16, cnt/hdr zero, weight packs, pq-bias -----
__global__ void __launch_bounds__(256) k_prep(const float* __restrict__ x,
    u16* __restrict__ Xb, int* __restrict__ cnt, int n4, int N,
    const float* __restrict__ win, const float* __restrict__ w1a,
    const float* __restrict__ w1b, const float* __restrict__ wout,
    const float* __restrict__ w2a, const float* __restrict__ w2b,
    const float* __restrict__ b1a, const float* __restrict__ b1b,
    u16* __restrict__ WTin, u16* __restrict__ WT1a, u16* __restrict__ WT1b,
    u16* __restrict__ WTout, u16* __restrict__ W2Ta, u16* __restrict__ W2Tb,
    float* __restrict__ B1pa, float* __restrict__ B1pb,
    u16* __restrict__ hdr) {
  int idx = blockIdx.x * 256 + threadIdx.x;
  if (idx < N) cnt[idx] = 0;
  if (idx < N * 16) hdr[idx] = 0;  // pad rows -> node 0 (valid, unused)
  if (idx < n4) {
    float4 v = ((const float4*)x)[idx];
    ushort4 o;
    o.x = f2bf(v.x);
    o.y = f2bf(v.y);
    o.z = f2bf(v.z);
    o.w = f2bf(v.w);
    ((ushort4*)Xb)[idx] = o;
  }
  if (idx < 16384) {
    int o = idx >> 7, i = idx & 127;
    WTin[idx] = f2bf(win[i * 128 + o]);
  } else if (idx < 32768) {
    int j = idx - 16384;
    int o = j >> 7, i = j & 127;
    WT1a[j] = f2bf(o < 64 ? w1a[i * 64 + o] : w1a[(128 + i) * 64 + (o - 64)]);
  } else if (idx < 49152) {
    int j = idx - 32768;
    int o = j >> 7, i = j & 127;
    WT1b[j] = f2bf(o < 64 ? w1b[i * 64 + o] : w1b[(128 + i) * 64 + (o - 64)]);
  } else if (idx < 57344) {
    int j = idx - 49152;
    int o = j >> 7, i = j & 127;  // o < 64
    WTout[j] = f2bf(wout[i * 64 + o]);
  } else if (idx < 59392) {
    int j = idx - 57344;
    int o = j >> 6, k = j & 63;  // W2T[o][k] = w2[k][o]
    W2Ta[j] = f2bf(w2a[k * 32 + o]);
  } else if (idx < 61440) {
    int j = idx - 59392;
    int o = j >> 6, k = j & 63;
    W2Tb[j] = f2bf(w2b[k * 32 + o]);
  } else if (idx < 61568) {
    int j = idx - 61440;
    B1pa[j] = (j < 64) ? 0.f : b1a[j - 64];
  } else if (idx < 61696) {
    int j = idx - 61568;
    B1pb[j] = (j < 64) ? 0.f : b1b[j - 64];
  }
}

// ---- bf16 MFMA GEMM: wave = one 16x16 tile, K=128 --------------------------
__global__ void __launch_bounds__(256) k_gemm_mfma(const u16* __restrict__ Ab,
    const u16* __restrict__ WT, const float* __restrict__ bias,
    float* __restrict__ C, u16* __restrict__ Cb, int N, int P) {
  int t = threadIdx.x;
  int wv = t >> 6, lane = t & 63;
  int row0 = (blockIdx.x << 6) + (wv << 4);
  int cb = blockIdx.y << 4;
  int col = lane & 15, quad = lane >> 4;
  const u16* wrow = WT + (size_t)(cb + col) * 128 + quad * 8;
  short8 b0 = *(const short8*)(wrow);
  short8 b1 = *(const short8*)(wrow + 32);
  short8 b2 = *(const short8*)(wrow + 64);
  short8 b3 = *(const short8*)(wrow + 96);
  float bv = bias ? bias[cb + col] : 0.f;
  const u16* ar = Ab + (size_t)(row0 + col) * 128 + quad * 8;
  short8 a0 = *(const short8*)(ar);
  short8 a1 = *(const short8*)(ar + 32);
  short8 a2 = *(const short8*)(ar + 64);
  short8 a3 = *(const short8*)(ar + 96);
  f32x4 acc = {0.f, 0.f, 0.f, 0.f};
  acc = __builtin_amdgcn_mfma_f32_16x16x32_bf16(a0, b0, acc, 0, 0, 0);
  acc = __builtin_amdgcn_mfma_f32_16x16x32_bf16(a1, b1, acc, 0, 0, 0);
  acc = __builtin_amdgcn_mfma_f32_16x16x32_bf16(a2, b2, acc, 0, 0, 0);
  acc = __builtin_amdgcn_mfma_f32_16x16x32_bf16(a3, b3, acc, 0, 0, 0);
#pragma unroll
  for (int r = 0; r < 4; ++r) {
    int row = row0 + quad * 4 + r;
    if (row < N) {
      float o = acc[r] + bv;
      if (C) C[(size_t)row * P + cb + col] = o;
      if (Cb) Cb[(size_t)row * 128 + cb + col] = f2bf(o);
    }
  }
}

// ---- CSR build (by col): hist -> 2-phase scan -> fill ----------------------
__global__ void __launch_bounds__(256) k_hist(const int* __restrict__ eidx,
                                              int* __restrict__ cnt, int E) {
  int e = blockIdx.x * 256 + threadIdx.x;
  if (e < E) atomicAdd(&cnt[eidx[E + e]], 1);
}

__global__ void __launch_bounds__(256) k_scanA(const int* __restrict__ cnt,
                                               int* __restrict__ bsum, int N) {
  __shared__ int sums[256];
  int b = blockIdx.x, t = threadIdx.x;
  int base = b * 2048 + t * 8;
  int s = 0;
#pragma unroll
  for (int k = 0; k < 8; ++k) {
    int i = base + k;
    if (i < N) s += cnt[i];
  }
  sums[t] = s;
  __syncthreads();
  for (int d = 128; d > 0; d >>= 1) {
    if (t < d) sums[t] += sums[t + d];
    __syncthreads();
  }
  if (t == 0) bsum[b] = sums[0];
}

__global__ void __launch_bounds__(256) k_scanC(const int* __restrict__ cnt,
    const int* __restrict__ bsum, int* __restrict__ ptr,
    int* __restrict__ cursor, int N, int nblocks) {
  __shared__ int sums[256];
  int b = blockIdx.x, t = threadIdx.x;
  int bo = 0;
  for (int k = 0; k < b; ++k) bo += bsum[k];  // <=10 iterations
  int base = b * 2048 + t * 8;
  int vals[8];
  int s = 0;
#pragma unroll
  for (int k = 0; k < 8; ++k) {
    int i = base + k;
    int c = (i < N) ? cnt[i] : 0;
    vals[k] = s;
    s += c;
  }
  sums[t] = s;
  __syncthreads();
  for (int d = 1; d < 256; d <<= 1) {
    int v = (t >= d) ? sums[t - d] : 0;
    __syncthreads();
    sums[t] += v;
    __syncthreads();
  }
  int toff = (t == 0) ? 0 : sums[t - 1];
#pragma unroll
  for (int k = 0; k < 8; ++k) {
    int i = base + k;
    if (i < N) {
      int p = bo + toff + vals[k];
      ptr[i] = p;
      cursor[i] = p;
    }
  }
  if (b == nblocks - 1 && t == 255) ptr[N] = bo + sums[255];
}

// fill adj + the padded first-batch header (rows fit u16: N < 65536)
__global__ void __launch_bounds__(256) k_fill(const int* __restrict__ eidx,
    int* __restrict__ cursor, int* __restrict__ adj, u16* __restrict__ hdr,
    const int* __restrict__ ptr, int E) {
  int e = blockIdx.x * 256 + threadIdx.x;
  if (e >= E) return;
  int r = eidx[e], c = eidx[E + e];
  int pos = atomicAdd(&cursor[c], 1);
  adj[pos] = r;
  int local = pos - ptr[c];
  if ((unsigned)local < 16u) hdr[(size_t)c * 16 + local] = (u16)r;
}

// ---- exact expm of antisym 4x4 via so(4) = su(2) + su(2) -------------------
__device__ __forceinline__ void so4_expm(const float* __restrict__ m,
                                         float* __restrict__ F) {
  float v1 = m[1] - m[4], v2 = m[2] - m[8], v3 = m[3] - m[12];
  float w1 = m[11] - m[14], w2 = m[13] - m[7], w3 = m[6] - m[9];
  float p1 = 0.5f * (v1 + w1), p2 = 0.5f * (v2 + w2), p3 = 0.5f * (v3 + w3);
  float q1 = 0.5f * (v1 - w1), q2 = 0.5f * (v2 - w2), q3 = 0.5f * (v3 - w3);
  float tp2 = p1 * p1 + p2 * p2 + p3 * p3;
  float tq2 = q1 * q1 + q2 * q2 + q3 * q3;
  float tp = sqrtf(tp2), tq = sqrtf(tq2);
  float cp = __cosf(tp);
  float sp = (tp > 1e-6f) ? (__sinf(tp) / tp) : (1.f - tp2 * (1.f / 6.f));
  float cq = __cosf(tq);
  float sq = (tq > 1e-6f) ? (__sinf(tq) / tq) : (1.f - tq2 * (1.f / 6.f));
  float a1 = sp * p1, a2 = sp * p2, a3 = sp * p3;
  float b1 = sq * q1, b2 = sq * q2, b3 = sq * q3;
  float Rp[16] = {cp,  a1,  a2,  a3,  -a1, cp,  a3,  -a2,
                  -a2, -a3, cp,  a1,  -a3, a2,  -a1, cp};
  float Rq[16] = {cq,  b1,  b2,  b3,  -b1, cq,  -b3, b2,
                  -b2, b3,  cq,  -b1, -b3, -b2, b1,  cq};
#pragma unroll
  for (int a = 0; a < 4; ++a)
#pragma unroll
    for (int b = 0; b < 4; ++b) {
      float s = 0.f;
#pragma unroll
      for (int c = 0; c < 4; ++c) s = fmaf(Rp[a * 4 + c], Rq[c * 4 + b], s);
      F[a * 4 + b] = s;
    }
}

// ---- fused conv: one node per single-wave block, hdr entry + x prefetch ----
// Node entry: hdr rows + ptr load in PARALLEL (both direct-addressed).
// Per <=16-edge batch: P gathers direct (on the critical path anyway),
// MFMA h@w2, LDS transpose, lanes 0..15 expm, aggregation from LDS-staged
// x-rows (issued early, used late; T14). Per-wave lgkm fences only.
// Epilogue-only state (xi/hv) loaded AFTER the loop -> VGPR <= 64.
__global__ void __launch_bounds__(64) k_conv(const float* __restrict__ x,
    const u16* __restrict__ xgb, const u16* __restrict__ pqb,
    const u16* __restrict__ W2T, const float* __restrict__ b2,
    const int* __restrict__ ptr, const int* __restrict__ adj,
    const u16* __restrict__ hdr,
    const float* __restrict__ epsp, float* __restrict__ xout,
    u16* __restrict__ xoutb, int N) {
  __shared__ float ms[16 * 44];
  __shared__ u16 xs[2][16 * 128];  // staged xgb rows, double-buffered
  int lane = threadIdx.x;
  int v = blockIdx.x;
  if (v >= N) return;
  int el = lane & 15, quad = lane >> 4;
  // first-batch edge rows: direct-addressed -> issues parallel with ptr
  int row = (int)hdr[(size_t)v * 16 + el];
  int p0 = ptr[v], p1 = ptr[v + 1];
  int a = lane & 3, kb = lane & ~3;
  int xsub = lane >> 4;            // staging: row within 4-row group
  int xcol = (lane & 15) * 8;      // staging: u16 col offset (16B)
  // B-frags: w2^T, wave-invariant. B[n][k=quad*8+j].
  short8 bf00 = *(const short8*)(W2T + (size_t)el * 64 + quad * 8);
  short8 bf01 = *(const short8*)(W2T + (size_t)el * 64 + 32 + quad * 8);
  short8 bf10 = *(const short8*)(W2T + (size_t)(16 + el) * 64 + quad * 8);
  short8 bf11 = *(const short8*)(W2T + (size_t)(16 + el) * 64 + 32 + quad * 8);
  float b2a = b2[el], b2b = b2[16 + el];
  // q-part of h: col == v for every edge of this node (CSR order) -> uniform
  short8 qv0 = *(const short8*)(pqb + (size_t)v * 128 + 64 + quad * 8);
  short8 qv1 = *(const short8*)(pqb + (size_t)v * 128 + 96 + quad * 8);
  float s10 = 0.f, s11 = 0.f, s12 = 0.f, s13 = 0.f;  // sum of M1 row a
  float acc1 = 0.f, acc2 = 0.f;                       // -sum M2.x_r
  int cur = 0;
  if (p0 < p1) {  // prologue: stage batch 0's x-rows (hdr-derived, early)
#pragma unroll
    for (int t = 0; t < 4; ++t) {
      int r = __shfl(row, (t << 2) + xsub);
      glds16(xgb + (size_t)r * 128 + xcol, &xs[0][t * 512]);
    }
  }
  for (int b0 = p0; b0 < p1; b0 += 16) {
    int nb = p1 - b0;
    nb = (nb > 16) ? 16 : nb;
    int have_next = (b0 + 16 < p1);
    int row_n = row;
    if (have_next) {  // next batch rows from adj (minority of nodes)
      int nb2 = p1 - b0 - 16;
      nb2 = (nb2 > 16) ? 16 : nb2;
      int ee2 = b0 + 16 + ((el < nb2) ? el : (nb2 - 1));
      row_n = adj[ee2];
    }
    f32x4 c0 = {0.f, 0.f, 0.f, 0.f};
    f32x4 c1 = {0.f, 0.f, 0.f, 0.f};
    {  // k-chunk 0 (feats 0..31); b1 pre-folded into q via GEMM bias
      short8 pv = *(const short8*)(pqb + (size_t)row * 128 + quad * 8);
      union { short8 s; unsigned u[4]; } av;
#pragma unroll
      for (int j2 = 0; j2 < 4; ++j2) {
        float h0 = fmaxf(bf2f((u16)pv[2 * j2]) + bf2f((u16)qv0[2 * j2]), 0.f);
        float h1 = fmaxf(
            bf2f((u16)pv[2 * j2 + 1]) + bf2f((u16)qv0[2 * j2 + 1]), 0.f);
        unsigned r;
        asm("v_cvt_pk_bf16_f32 %0, %1, %2" : "=v"(r) : "v"(h0), "v"(h1));
        av.u[j2] = r;
      }
      c0 = __builtin_amdgcn_mfma_f32_16x16x32_bf16(av.s, bf00, c0, 0, 0, 0);
      c1 = __builtin_amdgcn_mfma_f32_16x16x32_bf16(av.s, bf10, c1, 0, 0, 0);
    }
    {  // k-chunk 1 (feats 32..63)
      short8 pv = *(const short8*)(pqb + (size_t)row * 128 + 32 + quad * 8);
      union { short8 s; unsigned u[4]; } av;
#pragma unroll
      for (int j2 = 0; j2 < 4; ++j2) {
        float h0 = fmaxf(bf2f((u16)pv[2 * j2]) + bf2f((u16)qv1[2 * j2]), 0.f);
        float h1 = fmaxf(
            bf2f((u16)pv[2 * j2 + 1]) + bf2f((u16)qv1[2 * j2 + 1]), 0.f);
        unsigned r;
        asm("v_cvt_pk_bf16_f32 %0, %1, %2" : "=v"(r) : "v"(h0), "v"(h1));
        av.u[j2] = r;
      }
      c0 = __builtin_amdgcn_mfma_f32_16x16x32_bf16(av.s, bf01, c0, 0, 0, 0);
      c1 = __builtin_amdgcn_mfma_f32_16x16x32_bf16(av.s, bf11, c1, 0, 0, 0);
    }
    // C layout: row(quad*4+r)=edge, col(el)=output. Transpose via LDS.
#pragma unroll
    for (int r = 0; r < 4; ++r) {
      ms[(quad * 4 + r) * 44 + el] = c0[r] + b2a;
      ms[(quad * 4 + r) * 44 + 16 + el] = c1[r] + b2b;
    }
    wave_sync();
    // stage NEXT batch's x-rows while expm+aggregation run
    if (have_next) {
#pragma unroll
      for (int t = 0; t < 4; ++t) {
        int r = __shfl(row_n, (t << 2) + xsub);
        glds16(xgb + (size_t)r * 128 + xcol, &xs[cur ^ 1][t * 512]);
      }
    }
    if (lane < 16) {
      float m[32];
      const float* mr = ms + lane * 44;
#pragma unroll
      for (int i = 0; i < 32; ++i) m[i] = mr[i];
      float Fu[16], Fv[16];
      so4_expm(m, Fu);
      so4_expm(m + 16, Fv);
      float* mw = ms + lane * 44;
#pragma unroll
      for (int aa = 0; aa < 4; ++aa)
#pragma unroll
        for (int bb = 0; bb < 4; ++bb) {
          float s1 = 0.f, s2 = 0.f;
#pragma unroll
          for (int cc = 0; cc < 4; ++cc) {
            s1 = fmaf(Fu[cc * 4 + aa], Fu[cc * 4 + bb], s1);  // Fu^T Fu
            s2 = fmaf(Fu[cc * 4 + aa], Fv[cc * 4 + bb], s2);  // Fu^T Fv
          }
          mw[aa * 4 + bb] = s1;
          mw[16 + aa * 4 + bb] = s2;
        }
    }
    wave_sync();
    // X(cur) resident (in-order retirement at the P-wait); counted fence
    // keeps next-batch stage in flight.
    if (have_next) {
      asm volatile("s_waitcnt vmcnt(4)" ::: "memory");
    } else {
      asm volatile("s_waitcnt vmcnt(0)" ::: "memory");
    }
    __builtin_amdgcn_sched_barrier(0);
    const u16* xc = xs[cur];
    int j = 0;
    for (; j + 1 < nb; j += 2) {
      float4 am1 = *(const float4*)(ms + j * 44 + a * 4);
      float4 am2 = *(const float4*)(ms + j * 44 + 16 + a * 4);
      float4 bm1 = *(const float4*)(ms + (j + 1) * 44 + a * 4);
      float4 bm2 = *(const float4*)(ms + (j + 1) * 44 + 16 + a * 4);
      ushort4 ya1 = *(const ushort4*)(xc + j * 128 + kb);
      ushort4 ya2 = *(const ushort4*)(xc + j * 128 + 64 + kb);
      ushort4 yb1 = *(const ushort4*)(xc + (j + 1) * 128 + kb);
      ushort4 yb2 = *(const ushort4*)(xc + (j + 1) * 128 + 64 + kb);
      s10 += am1.x + bm1.x;
      s11 += am1.y + bm1.y;
      s12 += am1.z + bm1.z;
      s13 += am1.w + bm1.w;
      acc1 -= am2.x * bf2f(ya1.x) + am2.y * bf2f(ya1.y) +
              am2.z * bf2f(ya1.z) + am2.w * bf2f(ya1.w);
      acc2 -= am2.x * bf2f(ya2.x) + am2.y * bf2f(ya2.y) +
              am2.z * bf2f(ya2.z) + am2.w * bf2f(ya2.w);
      acc1 -= bm2.x * bf2f(yb1.x) + bm2.y * bf2f(yb1.y) +
              bm2.z * bf2f(yb1.z) + bm2.w * bf2f(yb1.w);
      acc2 -= bm2.x * bf2f(yb2.x) + bm2.y * bf2f(yb2.y) +
              bm2.z * bf2f(yb2.z) + bm2.w * bf2f(yb2.w);
    }
    if (j < nb) {
      float4 am1 = *(const float4*)(ms + j * 44 + a * 4);
      float4 am2 = *(const float4*)(ms + j * 44 + 16 + a * 4);
      ushort4 ya1 = *(const ushort4*)(xc + j * 128 + kb);
      ushort4 ya2 = *(const ushort4*)(xc + j * 128 + 64 + kb);
      s10 += am1.x;
      s11 += am1.y;
      s12 += am1.z;
      s13 += am1.w;
      acc1 -= am2.x * bf2f(ya1.x) + am2.y * bf2f(ya1.y) +
              am2.z * bf2f(ya1.z) + am2.w * bf2f(ya1.w);
      acc2 -= am2.x * bf2f(ya2.x) + am2.y * bf2f(ya2.y) +
              am2.z * bf2f(ya2.z) + am2.w * bf2f(ya2.w);
    }
    wave_sync();  // ms + xs[cur] reused next batch (WAR)
    row = row_n;
    cur ^= 1;
  }
  // epilogue-only loads: kept OUT of the loop's live range (VGPR budget)
  const float* xv = x + (size_t)v * 128;
  float4 xi1 = *(const float4*)(xv + kb);
  float4 xi2 = *(const float4*)(xv + 64 + kb);
  float hv1 = xv[lane], hv2 = xv[64 + lane];
  acc1 += s10 * xi1.x + s11 * xi1.y + s12 * xi1.z + s13 * xi1.w;
  acc2 += s10 * xi2.x + s11 * xi2.y + s12 * xi2.z + s13 * xi2.w;
  float eps = *epsp;
  float r1 = hv1 - eps * acc1;
  float r2 = hv2 - eps * acc2;
  r1 = (r1 > 0.f) ? r1 : expm1f(r1);
  r2 = (r2 > 0.f) ? r2 : expm1f(r2);
  xout[(size_t)v * 128 + lane] = r1;
  xout[(size_t)v * 128 + 64 + lane] = r2;
  xoutb[(size_t)v * 128 + lane] = f2bf(r1);
  xoutb[(size_t)v * 128 + 64 + lane] = f2bf(r2);
}

extern "C" void kernel_launch(void* const* d_in, const int* in_sizes, int n_in,
                              void* d_out, int out_size, void* d_ws,
                              size_t ws_size, hipStream_t stream) {
  const float* x = (const float*)d_in[0];
  const int* eidx = (const int*)d_in[1];
  const float* lin_in_w = (const float*)d_in[2];
  const float* lin_in_b = (const float*)d_in[3];
  const float* c0w1 = (const float*)d_in[4];
  const float* c0b1 = (const float*)d_in[5];
  const float* c0w2 = (const float*)d_in[6];
  const float* c0b2 = (const float*)d_in[7];
  const float* c0eps = (const float*)d_in[8];
  const float* c1w1 = (const float*)d_in[9];
  const float* c1b1 = (const float*)d_in[10];
  const float* c1w2 = (const float*)d_in[11];
  const float* c1b2 = (const float*)d_in[12];
  const float* c1eps = (const float*)d_in[13];
  const float* lout_w = (const float*)d_in[14];
  const float* lout_b = (const float*)d_in[15];
  float* out = (float*)d_out;

  int N = in_sizes[0] / 128;
  int E = in_sizes[1] / 2;
  int Npad = N + 64;

  char* ws = (char*)d_ws;
  size_t szH = (size_t)N * 128 * 4;
  size_t szHb = (size_t)Npad * 128 * 2;
  float* H = (float*)ws;
  float* H2 = (float*)(ws + szH);
  u16* Xb = (u16*)(ws + 2 * szH);
  u16* Hb = (u16*)(ws + 2 * szH + szHb);
  u16* H2b = (u16*)(ws + 2 * szH + 2 * szHb);
  u16* PQb = (u16*)(ws + 2 * szH + 3 * szHb);
  u16* WTin = (u16*)(ws + 2 * szH + 4 * szHb);
  u16* WT1a = WTin + 16384;
  u16* WT1b = WT1a + 16384;
  u16* WTout = WT1b + 16384;
  u16* W2Ta = WTout + 8192;
  u16* W2Tb = W2Ta + 2048;
  float* B1pa = (float*)(W2Tb + 2048);
  float* B1pb = B1pa + 128;
  char* ip = (char*)(B1pb + 128);
  int* cnt = (int*)ip;                                   // N
  int* ptr = (int*)(ip + 4 * (size_t)(N + 64));          // N+1
  int* cursor = (int*)(ip + 8 * (size_t)(N + 64));       // N
  int* adj = (int*)(ip + 12 * (size_t)(N + 64));         // E ints
  int* bsum = (int*)(ip + 12 * (size_t)(N + 64) + 4 * (size_t)E);  // 64
  u16* hdr = (u16*)(ip + 12 * (size_t)(N + 64) + 4 * (size_t)E + 256);  // N*16

  dim3 blk(256);
  int gN = (N + 63) / 64;
  int gE = (E + 255) / 256;
  int nsb = (N + 2047) / 2048;

  // fused prep, CSR build
  k_prep<<<(N * 32 + 255) / 256, blk, 0, stream>>>(
      x, Xb, cnt, N * 32, N, lin_in_w, c0w1, c1w1, lout_w, c0w2, c1w2, c0b1,
      c1b1, WTin, WT1a, WT1b, WTout, W2Ta, W2Tb, B1pa, B1pb, hdr);
  k_hist<<<gE, blk, 0, stream>>>(eidx, cnt, E);
  k_scanA<<<nsb, blk, 0, stream>>>(cnt, bsum, N);
  k_scanC<<<nsb, blk, 0, stream>>>(cnt, bsum, ptr, cursor, N, nsb);
  k_fill<<<gE, blk, 0, stream>>>(eidx, cursor, adj, hdr, ptr, E);

  // h0 = x @ lin_in_w + b   (fp32 H + bf16 Hb)
  k_gemm_mfma<<<dim3(gN, 8), blk, 0, stream>>>(Xb, WTin, lin_in_b, H, Hb, N,
                                               128);

  float* cur = H;
  float* nxt = H2;
  u16* curb = Hb;
  u16* nxtb = H2b;
  for (int layer = 0; layer < 2; ++layer) {
    const u16* wt1 = layer ? WT1b : WT1a;
    const u16* w2t = layer ? W2Tb : W2Ta;
    const float* b1p = layer ? B1pb : B1pa;
    const float* b2 = layer ? c1b2 : c0b2;
    const float* ep = layer ? c1eps : c0eps;
    // pq = h @ W1p + [0|b1]  (bf16 only)
    k_gemm_mfma<<<dim3(gN, 8), blk, 0, stream>>>(curb, wt1, b1p, nullptr, PQb,
                                                 N, 128);
    k_conv<<<N, dim3(64), 0, stream>>>(cur, curb, PQb, w2t, b2, ptr, adj, hdr,
                                       ep, nxt, nxtb, N);
    float* tf = cur; cur = nxt; nxt = tf;
    u16* tb = curb; curb = nxtb; nxtb = tb;
  }

  // out = h @ lin_out_w + b
  k_gemm_mfma<<<dim3(gN, 4), blk, 0, stream>>>(curb, WTout, lout_b, out,
                                               nullptr, N, 64);
}

// Round 10
// 263.089 us; speedup vs baseline: 1.0501x; 1.0501x over previous
//
#include <hip/hip_runtime.h>
#include <math.h>

// ---------------------------------------------------------------------------
// SheafGNN forward. R24 = R22 (best: 273.5us, k_conv 54.4us) +
//  - k_conv expm phase spread over 32 lanes: lane hi*16+el computes ONE
//    so4_expm (hi=0: Fu, hi=1: Fv of edge el), Fu broadcast pair-wise via
//    16 __shfl, then M1=Fu^T Fu (lanes 0-15) / M2=Fu^T Fv (lanes 16-31)
//    computed in parallel (uniform code: left=shfl'd fu, right=own F).
//    Halves the serial expm chain AND the branch's register high-water
//    (was m[32]+Fu[16]+Fv[16]=64 floats in one lane -> ~36).
//  - R23 epilogue-move REVERTED (VGPR only 72->68, still >64 cliff; reload
//    chain cost +2.7us).
// Pinned: 1-wave WGs; hdr parallel entry; xs dbuf staging + counted vmcnt;
// per-wave lgkm fences; never force occupancy via launch_bounds (R18).
// ---------------------------------------------------------------------------

using short8 = __attribute__((ext_vector_type(8))) short;
using f32x4 = __attribute__((ext_vector_type(4))) float;
typedef unsigned short u16;

__device__ __forceinline__ u16 f2bf(float f) {  // RNE fp32->bf16
  unsigned u = __float_as_uint(f);
  unsigned r = (u + 0x7FFFu + ((u >> 16) & 1u)) >> 16;
  return (u16)r;
}
__device__ __forceinline__ float bf2f(u16 v) {
  return __uint_as_float(((unsigned)v) << 16);
}

// per-wave LDS fence (1-wave block): orders ds_write -> ds_read without
// draining vmcnt (keeps global_load_lds prefetches in flight).
__device__ __forceinline__ void wave_sync() {
  __builtin_amdgcn_sched_barrier(0);
  asm volatile("s_waitcnt lgkmcnt(0)" ::: "memory");
  __builtin_amdgcn_sched_barrier(0);
}

// async 16B/lane global->LDS: HW dest = lds_base + lane*16 (wave-uniform
// base); global src is per-lane. Tracked by vmcnt.
__device__ __forceinline__ void glds16(const void* g, void* l) {
  __builtin_amdgcn_global_load_lds(
      (const __attribute__((address_space(1))) unsigned int*)g,
      (__attribute__((address_space(3))) unsigned int*)l, 16, 0, 0);
}

// ---- fused one-time prep: x->bf16, cnt/hdr zero, weight packs, pq-bias -----
__global__ void __launch_bounds__(256) k_prep(const float* __restrict__ x,
    u16* __restrict__ Xb, int* __restrict__ cnt, int n4, int N,
    const float* __restrict__ win, const float* __restrict__ w1a,
    const float* __restrict__ w1b, const float* __restrict__ wout,
    const float* __restrict__ w2a, const float* __restrict__ w2b,
    const float* __restrict__ b1a, const float* __restrict__ b1b,
    u16* __restrict__ WTin, u16* __restrict__ WT1a, u16* __restrict__ WT1b,
    u16* __restrict__ WTout, u16* __restrict__ W2Ta, u16* __restrict__ W2Tb,
    float* __restrict__ B1pa, float* __restrict__ B1pb,
    u16* __restrict__ hdr) {
  int idx = blockIdx.x * 256 + threadIdx.x;
  if (idx < N) cnt[idx] = 0;
  if (idx < N * 16) hdr[idx] = 0;  // pad rows -> node 0 (valid, unused)
  if (idx < n4) {
    float4 v = ((const float4*)x)[idx];
    ushort4 o;
    o.x = f2bf(v.x);
    o.y = f2bf(v.y);
    o.z = f2bf(v.z);
    o.w = f2bf(v.w);
    ((ushort4*)Xb)[idx] = o;
  }
  if (idx < 16384) {
    int o = idx >> 7, i = idx & 127;
    WTin[idx] = f2bf(win[i * 128 + o]);
  } else if (idx < 32768) {
    int j = idx - 16384;
    int o = j >> 7, i = j & 127;
    WT1a[j] = f2bf(o < 64 ? w1a[i * 64 + o] : w1a[(128 + i) * 64 + (o - 64)]);
  } else if (idx < 49152) {
    int j = idx - 32768;
    int o = j >> 7, i = j & 127;
    WT1b[j] = f2bf(o < 64 ? w1b[i * 64 + o] : w1b[(128 + i) * 64 + (o - 64)]);
  } else if (idx < 57344) {
    int j = idx - 49152;
    int o = j >> 7, i = j & 127;  // o < 64
    WTout[j] = f2bf(wout[i * 64 + o]);
  } else if (idx < 59392) {
    int j = idx - 57344;
    int o = j >> 6, k = j & 63;  // W2T[o][k] = w2[k][o]
    W2Ta[j] = f2bf(w2a[k * 32 + o]);
  } else if (idx < 61440) {
    int j = idx - 59392;
    int o = j >> 6, k = j & 63;
    W2Tb[j] = f2bf(w2b[k * 32 + o]);
  } else if (idx < 61568) {
    int j = idx - 61440;
    B1pa[j] = (j < 64) ? 0.f : b1a[j - 64];
  } else if (idx < 61696) {
    int j = idx - 61568;
    B1pb[j] = (j < 64) ? 0.f : b1b[j - 64];
  }
}

// ---- bf16 MFMA GEMM: wave = one 16x16 tile, K=128 --------------------------
__global__ void __launch_bounds__(256) k_gemm_mfma(const u16* __restrict__ Ab,
    const u16* __restrict__ WT, const float* __restrict__ bias,
    float* __restrict__ C, u16* __restrict__ Cb, int N, int P) {
  int t = threadIdx.x;
  int wv = t >> 6, lane = t & 63;
  int row0 = (blockIdx.x << 6) + (wv << 4);
  int cb = blockIdx.y << 4;
  int col = lane & 15, quad = lane >> 4;
  const u16* wrow = WT + (size_t)(cb + col) * 128 + quad * 8;
  short8 b0 = *(const short8*)(wrow);
  short8 b1 = *(const short8*)(wrow + 32);
  short8 b2 = *(const short8*)(wrow + 64);
  short8 b3 = *(const short8*)(wrow + 96);
  float bv = bias ? bias[cb + col] : 0.f;
  const u16* ar = Ab + (size_t)(row0 + col) * 128 + quad * 8;
  short8 a0 = *(const short8*)(ar);
  short8 a1 = *(const short8*)(ar + 32);
  short8 a2 = *(const short8*)(ar + 64);
  short8 a3 = *(const short8*)(ar + 96);
  f32x4 acc = {0.f, 0.f, 0.f, 0.f};
  acc = __builtin_amdgcn_mfma_f32_16x16x32_bf16(a0, b0, acc, 0, 0, 0);
  acc = __builtin_amdgcn_mfma_f32_16x16x32_bf16(a1, b1, acc, 0, 0, 0);
  acc = __builtin_amdgcn_mfma_f32_16x16x32_bf16(a2, b2, acc, 0, 0, 0);
  acc = __builtin_amdgcn_mfma_f32_16x16x32_bf16(a3, b3, acc, 0, 0, 0);
#pragma unroll
  for (int r = 0; r < 4; ++r) {
    int row = row0 + quad * 4 + r;
    if (row < N) {
      float o = acc[r] + bv;
      if (C) C[(size_t)row * P + cb + col] = o;
      if (Cb) Cb[(size_t)row * 128 + cb + col] = f2bf(o);
    }
  }
}

// ---- CSR build (by col): hist -> 2-phase scan -> fill ----------------------
__global__ void __launch_bounds__(256) k_hist(const int* __restrict__ eidx,
                                              int* __restrict__ cnt, int E) {
  int e = blockIdx.x * 256 + threadIdx.x;
  if (e < E) atomicAdd(&cnt[eidx[E + e]], 1);
}

__global__ void __launch_bounds__(256) k_scanA(const int* __restrict__ cnt,
                                               int* __restrict__ bsum, int N) {
  __shared__ int sums[256];
  int b = blockIdx.x, t = threadIdx.x;
  int base = b * 2048 + t * 8;
  int s = 0;
#pragma unroll
  for (int k = 0; k < 8; ++k) {
    int i = base + k;
    if (i < N) s += cnt[i];
  }
  sums[t] = s;
  __syncthreads();
  for (int d = 128; d > 0; d >>= 1) {
    if (t < d) sums[t] += sums[t + d];
    __syncthreads();
  }
  if (t == 0) bsum[b] = sums[0];
}

__global__ void __launch_bounds__(256) k_scanC(const int* __restrict__ cnt,
    const int* __restrict__ bsum, int* __restrict__ ptr,
    int* __restrict__ cursor, int N, int nblocks) {
  __shared__ int sums[256];
  int b = blockIdx.x, t = threadIdx.x;
  int bo = 0;
  for (int k = 0; k < b; ++k) bo += bsum[k];  // <=10 iterations
  int base = b * 2048 + t * 8;
  int vals[8];
  int s = 0;
#pragma unroll
  for (int k = 0; k < 8; ++k) {
    int i = base + k;
    int c = (i < N) ? cnt[i] : 0;
    vals[k] = s;
    s += c;
  }
  sums[t] = s;
  __syncthreads();
  for (int d = 1; d < 256; d <<= 1) {
    int v = (t >= d) ? sums[t - d] : 0;
    __syncthreads();
    sums[t] += v;
    __syncthreads();
  }
  int toff = (t == 0) ? 0 : sums[t - 1];
#pragma unroll
  for (int k = 0; k < 8; ++k) {
    int i = base + k;
    if (i < N) {
      int p = bo + toff + vals[k];
      ptr[i] = p;
      cursor[i] = p;
    }
  }
  if (b == nblocks - 1 && t == 255) ptr[N] = bo + sums[255];
}

// fill adj + the padded first-batch header (rows fit u16: N < 65536)
__global__ void __launch_bounds__(256) k_fill(const int* __restrict__ eidx,
    int* __restrict__ cursor, int* __restrict__ adj, u16* __restrict__ hdr,
    const int* __restrict__ ptr, int E) {
  int e = blockIdx.x * 256 + threadIdx.x;
  if (e >= E) return;
  int r = eidx[e], c = eidx[E + e];
  int pos = atomicAdd(&cursor[c], 1);
  adj[pos] = r;
  int local = pos - ptr[c];
  if ((unsigned)local < 16u) hdr[(size_t)c * 16 + local] = (u16)r;
}

// ---- exact expm of antisym 4x4 via so(4) = su(2) + su(2) -------------------
__device__ __forceinline__ void so4_expm(const float* __restrict__ m,
                                         float* __restrict__ F) {
  float v1 = m[1] - m[4], v2 = m[2] - m[8], v3 = m[3] - m[12];
  float w1 = m[11] - m[14], w2 = m[13] - m[7], w3 = m[6] - m[9];
  float p1 = 0.5f * (v1 + w1), p2 = 0.5f * (v2 + w2), p3 = 0.5f * (v3 + w3);
  float q1 = 0.5f * (v1 - w1), q2 = 0.5f * (v2 - w2), q3 = 0.5f * (v3 - w3);
  float tp2 = p1 * p1 + p2 * p2 + p3 * p3;
  float tq2 = q1 * q1 + q2 * q2 + q3 * q3;
  float tp = sqrtf(tp2), tq = sqrtf(tq2);
  float cp = __cosf(tp);
  float sp = (tp > 1e-6f) ? (__sinf(tp) / tp) : (1.f - tp2 * (1.f / 6.f));
  float cq = __cosf(tq);
  float sq = (tq > 1e-6f) ? (__sinf(tq) / tq) : (1.f - tq2 * (1.f / 6.f));
  float a1 = sp * p1, a2 = sp * p2, a3 = sp * p3;
  float b1 = sq * q1, b2 = sq * q2, b3 = sq * q3;
  float Rp[16] = {cp,  a1,  a2,  a3,  -a1, cp,  a3,  -a2,
                  -a2, -a3, cp,  a1,  -a3, a2,  -a1, cp};
  float Rq[16] = {cq,  b1,  b2,  b3,  -b1, cq,  -b3, b2,
                  -b2, b3,  cq,  -b1, -b3, -b2, b1,  cq};
#pragma unroll
  for (int a = 0; a < 4; ++a)
#pragma unroll
    for (int b = 0; b < 4; ++b) {
      float s = 0.f;
#pragma unroll
      for (int c = 0; c < 4; ++c) s = fmaf(Rp[a * 4 + c], Rq[c * 4 + b], s);
      F[a * 4 + b] = s;
    }
}

// ---- fused conv: one node per single-wave block, hdr entry + x prefetch ----
// Node entry: hdr rows + ptr load in PARALLEL. Per <=16-edge batch: P
// gathers direct, MFMA h@w2, LDS transpose; expm SPREAD over 32 lanes
// (lane hi*16+el: one so4_expm each; Fu broadcast via shfl; M1/M2 products
// in parallel); aggregation from LDS-staged x-rows. Per-wave lgkm fences.
__global__ void __launch_bounds__(64) k_conv(const float* __restrict__ x,
    const u16* __restrict__ xgb, const u16* __restrict__ pqb,
    const u16* __restrict__ W2T, const float* __restrict__ b2,
    const int* __restrict__ ptr, const int* __restrict__ adj,
    const u16* __restrict__ hdr,
    const float* __restrict__ epsp, float* __restrict__ xout,
    u16* __restrict__ xoutb, int N) {
  __shared__ float ms[16 * 44];
  __shared__ u16 xs[2][16 * 128];  // staged xgb rows, double-buffered
  int lane = threadIdx.x;
  int v = blockIdx.x;
  if (v >= N) return;
  int el = lane & 15, quad = lane >> 4;
  // first-batch edge rows: direct-addressed -> issues parallel with ptr
  int row = (int)hdr[(size_t)v * 16 + el];
  int p0 = ptr[v], p1 = ptr[v + 1];
  int a = lane & 3, kb = lane & ~3;
  int xsub = lane >> 4;            // staging: row within 4-row group
  int xcol = (lane & 15) * 8;      // staging: u16 col offset (16B)
  // B-frags: w2^T, wave-invariant. B[n][k=quad*8+j].
  short8 bf00 = *(const short8*)(W2T + (size_t)el * 64 + quad * 8);
  short8 bf01 = *(const short8*)(W2T + (size_t)el * 64 + 32 + quad * 8);
  short8 bf10 = *(const short8*)(W2T + (size_t)(16 + el) * 64 + quad * 8);
  short8 bf11 = *(const short8*)(W2T + (size_t)(16 + el) * 64 + 32 + quad * 8);
  float b2a = b2[el], b2b = b2[16 + el];
  // q-part of h: col == v for every edge of this node (CSR order) -> uniform
  short8 qv0 = *(const short8*)(pqb + (size_t)v * 128 + 64 + quad * 8);
  short8 qv1 = *(const short8*)(pqb + (size_t)v * 128 + 96 + quad * 8);
  const float* xv = x + (size_t)v * 128;
  float4 xi1 = *(const float4*)(xv + kb);
  float4 xi2 = *(const float4*)(xv + 64 + kb);
  float hv1 = xv[lane], hv2 = xv[64 + lane];
  float s10 = 0.f, s11 = 0.f, s12 = 0.f, s13 = 0.f;  // sum of M1 row a
  float acc1 = 0.f, acc2 = 0.f;                       // -sum M2.x_r
  int cur = 0;
  if (p0 < p1) {  // prologue: stage batch 0's x-rows (hdr-derived, early)
#pragma unroll
    for (int t = 0; t < 4; ++t) {
      int r = __shfl(row, (t << 2) + xsub);
      glds16(xgb + (size_t)r * 128 + xcol, &xs[0][t * 512]);
    }
  }
  for (int b0 = p0; b0 < p1; b0 += 16) {
    int nb = p1 - b0;
    nb = (nb > 16) ? 16 : nb;
    int have_next = (b0 + 16 < p1);
    int row_n = row;
    if (have_next) {  // next batch rows from adj (minority of nodes)
      int nb2 = p1 - b0 - 16;
      nb2 = (nb2 > 16) ? 16 : nb2;
      int ee2 = b0 + 16 + ((el < nb2) ? el : (nb2 - 1));
      row_n = adj[ee2];
    }
    f32x4 c0 = {0.f, 0.f, 0.f, 0.f};
    f32x4 c1 = {0.f, 0.f, 0.f, 0.f};
    {  // k-chunk 0 (feats 0..31); b1 pre-folded into q via GEMM bias
      short8 pv = *(const short8*)(pqb + (size_t)row * 128 + quad * 8);
      union { short8 s; unsigned u[4]; } av;
#pragma unroll
      for (int j2 = 0; j2 < 4; ++j2) {
        float h0 = fmaxf(bf2f((u16)pv[2 * j2]) + bf2f((u16)qv0[2 * j2]), 0.f);
        float h1 = fmaxf(
            bf2f((u16)pv[2 * j2 + 1]) + bf2f((u16)qv0[2 * j2 + 1]), 0.f);
        unsigned r;
        asm("v_cvt_pk_bf16_f32 %0, %1, %2" : "=v"(r) : "v"(h0), "v"(h1));
        av.u[j2] = r;
      }
      c0 = __builtin_amdgcn_mfma_f32_16x16x32_bf16(av.s, bf00, c0, 0, 0, 0);
      c1 = __builtin_amdgcn_mfma_f32_16x16x32_bf16(av.s, bf10, c1, 0, 0, 0);
    }
    {  // k-chunk 1 (feats 32..63)
      short8 pv = *(const short8*)(pqb + (size_t)row * 128 + 32 + quad * 8);
      union { short8 s; unsigned u[4]; } av;
#pragma unroll
      for (int j2 = 0; j2 < 4; ++j2) {
        float h0 = fmaxf(bf2f((u16)pv[2 * j2]) + bf2f((u16)qv1[2 * j2]), 0.f);
        float h1 = fmaxf(
            bf2f((u16)pv[2 * j2 + 1]) + bf2f((u16)qv1[2 * j2 + 1]), 0.f);
        unsigned r;
        asm("v_cvt_pk_bf16_f32 %0, %1, %2" : "=v"(r) : "v"(h0), "v"(h1));
        av.u[j2] = r;
      }
      c0 = __builtin_amdgcn_mfma_f32_16x16x32_bf16(av.s, bf01, c0, 0, 0, 0);
      c1 = __builtin_amdgcn_mfma_f32_16x16x32_bf16(av.s, bf11, c1, 0, 0, 0);
    }
    // C layout: row(quad*4+r)=edge, col(el)=output. Transpose via LDS.
#pragma unroll
    for (int r = 0; r < 4; ++r) {
      ms[(quad * 4 + r) * 44 + el] = c0[r] + b2a;
      ms[(quad * 4 + r) * 44 + 16 + el] = c1[r] + b2b;
    }
    wave_sync();
    // stage NEXT batch's x-rows while expm+aggregation run
    if (have_next) {
#pragma unroll
      for (int t = 0; t < 4; ++t) {
        int r = __shfl(row_n, (t << 2) + xsub);
        glds16(xgb + (size_t)r * 128 + xcol, &xs[cur ^ 1][t * 512]);
      }
    }
    // expm spread over 32 lanes: lane hi*16+el does ONE so4_expm.
    if (lane < 32) {
      int hi = quad;  // 0: Fu (cols 0..15), 1: Fv (cols 16..31)
      const float* mr = ms + el * 44 + hi * 16;
      float mloc[16];
#pragma unroll
      for (int i = 0; i < 4; ++i)
        *(float4*)(mloc + 4 * i) = *(const float4*)(mr + 4 * i);
      float F[16];
      so4_expm(mloc, F);
      // broadcast Fu (held by lane el) to the whole pair; for hi=0 this
      // is a self-copy, so the product below is uniform: M = fu^T F
      // (hi=0: Fu^T Fu = M1; hi=1: Fu^T Fv = M2).
      float fu[16];
#pragma unroll
      for (int i = 0; i < 16; ++i) fu[i] = __shfl(F[i], el);
      float res[16];
#pragma unroll
      for (int aa = 0; aa < 4; ++aa)
#pragma unroll
        for (int bb = 0; bb < 4; ++bb) {
          float s = 0.f;
#pragma unroll
          for (int cc = 0; cc < 4; ++cc)
            s = fmaf(fu[cc * 4 + aa], F[cc * 4 + bb], s);
          res[aa * 4 + bb] = s;
        }
      float* mw = ms + el * 44 + hi * 16;
#pragma unroll
      for (int i = 0; i < 4; ++i)
        *(float4*)(mw + 4 * i) = *(const float4*)(res + 4 * i);
    }
    wave_sync();
    // X(cur) resident (in-order retirement); counted fence keeps
    // next-batch stage in flight.
    if (have_next) {
      asm volatile("s_waitcnt vmcnt(4)" ::: "memory");
    } else {
      asm volatile("s_waitcnt vmcnt(0)" ::: "memory");
    }
    __builtin_amdgcn_sched_barrier(0);
    const u16* xc = xs[cur];
    int j = 0;
    for (; j + 1 < nb; j += 2) {
      float4 am1 = *(const float4*)(ms + j * 44 + a * 4);
      float4 am2 = *(const float4*)(ms + j * 44 + 16 + a * 4);
      float4 bm1 = *(const float4*)(ms + (j + 1) * 44 + a * 4);
      float4 bm2 = *(const float4*)(ms + (j + 1) * 44 + 16 + a * 4);
      ushort4 ya1 = *(const ushort4*)(xc + j * 128 + kb);
      ushort4 ya2 = *(const ushort4*)(xc + j * 128 + 64 + kb);
      ushort4 yb1 = *(const ushort4*)(xc + (j + 1) * 128 + kb);
      ushort4 yb2 = *(const ushort4*)(xc + (j + 1) * 128 + 64 + kb);
      s10 += am1.x + bm1.x;
      s11 += am1.y + bm1.y;
      s12 += am1.z + bm1.z;
      s13 += am1.w + bm1.w;
      acc1 -= am2.x * bf2f(ya1.x) + am2.y * bf2f(ya1.y) +
              am2.z * bf2f(ya1.z) + am2.w * bf2f(ya1.w);
      acc2 -= am2.x * bf2f(ya2.x) + am2.y * bf2f(ya2.y) +
              am2.z * bf2f(ya2.z) + am2.w * bf2f(ya2.w);
      acc1 -= bm2.x * bf2f(yb1.x) + bm2.y * bf2f(yb1.y) +
              bm2.z * bf2f(yb1.z) + bm2.w * bf2f(yb1.w);
      acc2 -= bm2.x * bf2f(yb2.x) + bm2.y * bf2f(yb2.y) +
              bm2.z * bf2f(yb2.z) + bm2.w * bf2f(yb2.w);
    }
    if (j < nb) {
      float4 am1 = *(const float4*)(ms + j * 44 + a * 4);
      float4 am2 = *(const float4*)(ms + j * 44 + 16 + a * 4);
      ushort4 ya1 = *(const ushort4*)(xc + j * 128 + kb);
      ushort4 ya2 = *(const ushort4*)(xc + j * 128 + 64 + kb);
      s10 += am1.x;
      s11 += am1.y;
      s12 += am1.z;
      s13 += am1.w;
      acc1 -= am2.x * bf2f(ya1.x) + am2.y * bf2f(ya1.y) +
              am2.z * bf2f(ya1.z) + am2.w * bf2f(ya1.w);
      acc2 -= am2.x * bf2f(ya2.x) + am2.y * bf2f(ya2.y) +
              am2.z * bf2f(ya2.z) + am2.w * bf2f(ya2.w);
    }
    wave_sync();  // ms + xs[cur] reused next batch (WAR)
    row = row_n;
    cur ^= 1;
  }
  acc1 += s10 * xi1.x + s11 * xi1.y + s12 * xi1.z + s13 * xi1.w;
  acc2 += s10 * xi2.x + s11 * xi2.y + s12 * xi2.z + s13 * xi2.w;
  float eps = *epsp;
  float r1 = hv1 - eps * acc1;
  float r2 = hv2 - eps * acc2;
  r1 = (r1 > 0.f) ? r1 : expm1f(r1);
  r2 = (r2 > 0.f) ? r2 : expm1f(r2);
  xout[(size_t)v * 128 + lane] = r1;
  xout[(size_t)v * 128 + 64 + lane] = r2;
  xoutb[(size_t)v * 128 + lane] = f2bf(r1);
  xoutb[(size_t)v * 128 + 64 + lane] = f2bf(r2);
}

extern "C" void kernel_launch(void* const* d_in, const int* in_sizes, int n_in,
                              void* d_out, int out_size, void* d_ws,
                              size_t ws_size, hipStream_t stream) {
  const float* x = (const float*)d_in[0];
  const int* eidx = (const int*)d_in[1];
  const float* lin_in_w = (const float*)d_in[2];
  const float* lin_in_b = (const float*)d_in[3];
  const float* c0w1 = (const float*)d_in[4];
  const float* c0b1 = (const float*)d_in[5];
  const float* c0w2 = (const float*)d_in[6];
  const float* c0b2 = (const float*)d_in[7];
  const float* c0eps = (const float*)d_in[8];
  const float* c1w1 = (const float*)d_in[9];
  const float* c1b1 = (const float*)d_in[10];
  const float* c1w2 = (const float*)d_in[11];
  const float* c1b2 = (const float*)d_in[12];
  const float* c1eps = (const float*)d_in[13];
  const float* lout_w = (const float*)d_in[14];
  const float* lout_b = (const float*)d_in[15];
  float* out = (float*)d_out;

  int N = in_sizes[0] / 128;
  int E = in_sizes[1] / 2;
  int Npad = N + 64;

  char* ws = (char*)d_ws;
  size_t szH = (size_t)N * 128 * 4;
  size_t szHb = (size_t)Npad * 128 * 2;
  float* H = (float*)ws;
  float* H2 = (float*)(ws + szH);
  u16* Xb = (u16*)(ws + 2 * szH);
  u16* Hb = (u16*)(ws + 2 * szH + szHb);
  u16* H2b = (u16*)(ws + 2 * szH + 2 * szHb);
  u16* PQb = (u16*)(ws + 2 * szH + 3 * szHb);
  u16* WTin = (u16*)(ws + 2 * szH + 4 * szHb);
  u16* WT1a = WTin + 16384;
  u16* WT1b = WT1a + 16384;
  u16* WTout = WT1b + 16384;
  u16* W2Ta = WTout + 8192;
  u16* W2Tb = W2Ta + 2048;
  float* B1pa = (float*)(W2Tb + 2048);
  float* B1pb = B1pa + 128;
  char* ip = (char*)(B1pb + 128);
  int* cnt = (int*)ip;                                   // N
  int* ptr = (int*)(ip + 4 * (size_t)(N + 64));          // N+1
  int* cursor = (int*)(ip + 8 * (size_t)(N + 64));       // N
  int* adj = (int*)(ip + 12 * (size_t)(N + 64));         // E ints
  int* bsum = (int*)(ip + 12 * (size_t)(N + 64) + 4 * (size_t)E);  // 64
  u16* hdr = (u16*)(ip + 12 * (size_t)(N + 64) + 4 * (size_t)E + 256);  // N*16

  dim3 blk(256);
  int gN = (N + 63) / 64;
  int gE = (E + 255) / 256;
  int nsb = (N + 2047) / 2048;

  // fused prep, CSR build
  k_prep<<<(N * 32 + 255) / 256, blk, 0, stream>>>(
      x, Xb, cnt, N * 32, N, lin_in_w, c0w1, c1w1, lout_w, c0w2, c1w2, c0b1,
      c1b1, WTin, WT1a, WT1b, WTout, W2Ta, W2Tb, B1pa, B1pb, hdr);
  k_hist<<<gE, blk, 0, stream>>>(eidx, cnt, E);
  k_scanA<<<nsb, blk, 0, stream>>>(cnt, bsum, N);
  k_scanC<<<nsb, blk, 0, stream>>>(cnt, bsum, ptr, cursor, N, nsb);
  k_fill<<<gE, blk, 0, stream>>>(eidx, cursor, adj, hdr, ptr, E);

  // h0 = x @ lin_in_w + b   (fp32 H + bf16 Hb)
  k_gemm_mfma<<<dim3(gN, 8), blk, 0, stream>>>(Xb, WTin, lin_in_b, H, Hb, N,
                                               128);

  float* cur = H;
  float* nxt = H2;
  u16* curb = Hb;
  u16* nxtb = H2b;
  for (int layer = 0; layer < 2; ++layer) {
    const u16* wt1 = layer ? WT1b : WT1a;
    const u16* w2t = layer ? W2Tb : W2Ta;
    const float* b1p = layer ? B1pb : B1pa;
    const float* b2 = layer ? c1b2 : c0b2;
    const float* ep = layer ? c1eps : c0eps;
    // pq = h @ W1p + [0|b1]  (bf16 only)
    k_gemm_mfma<<<dim3(gN, 8), blk, 0, stream>>>(curb, wt1, b1p, nullptr, PQb,
                                                 N, 128);
    k_conv<<<N, dim3(64), 0, stream>>>(cur, curb, PQb, w2t, b2, ptr, adj, hdr,
                                       ep, nxt, nxtb, N);
    float* tf = cur; cur = nxt; nxt = tf;
    u16* tb = curb; curb = nxtb; nxtb = tb;
  }

  // out = h @ lin_out_w + b
  k_gemm_mfma<<<dim3(gN, 4), blk, 0, stream>>>(curb, WTout, lout_b, out,
                                               nullptr, N, 64);
}